// Round 14
// baseline (416.371 us; speedup 1.0000x reference)
//
#include <hip/hip_runtime.h>
#include <stdint.h>

typedef _Float16 f16;
typedef _Float16 f16x4 __attribute__((ext_vector_type(4)));
typedef _Float16 f16x8 __attribute__((ext_vector_type(8)));
typedef float    f32x4 __attribute__((ext_vector_type(4)));

__device__ __forceinline__ void llds16(const void* g, void* l) {
    __builtin_amdgcn_global_load_lds(
        (const __attribute__((address_space(1))) void*)g,
        (__attribute__((address_space(3))) void*)l, 16, 0, 0);
}

__device__ __forceinline__ unsigned long long pack_key(float s, int j) {
    unsigned u = __float_as_uint(s);
    u = (u & 0x80000000u) ? ~u : (u | 0x80000000u);
    return ((unsigned long long)u << 32) | (unsigned)(~(unsigned)j);
}

// ---------------- convert emb -> Bh fp16 + plain rinv ----------------
__global__ void convert_emb_kernel(const float* __restrict__ emb,
                                   f16* __restrict__ bh,
                                   float* __restrict__ rinv, int V, int E) {
    int row  = blockIdx.x * (blockDim.x >> 6) + (threadIdx.x >> 6);
    int lane = threadIdx.x & 63;
    if (row >= V) return;
    const float4* p = (const float4*)(emb + (size_t)row * E);
    int n4 = E >> 2;
    float ss = 0.f;
    for (int i = lane; i < n4; i += 64) {
        float4 v = p[i];
        ss = fmaf(v.x, v.x, ss); ss = fmaf(v.y, v.y, ss);
        ss = fmaf(v.z, v.z, ss); ss = fmaf(v.w, v.w, ss);
    }
    #pragma unroll
    for (int o = 32; o > 0; o >>= 1) ss += __shfl_down(ss, o, 64);
    if (lane == 0) rinv[row] = 1.0f / sqrtf(ss);

    for (int i = lane; i < n4; i += 64) {
        float4 v = p[i];
        f16x4 h;
        h.x = (f16)v.x; h.y = (f16)v.y; h.z = (f16)v.z; h.w = (f16)v.w;
        *(f16x4*)&bh[(size_t)row * E + i * 4] = h;
    }
}

// ---------------- convert batch -> Ah fp16 ----------------
__global__ void convert_batch_kernel(const float* __restrict__ batch,
                                     f16* __restrict__ ah, int M, int E) {
    int row  = blockIdx.x * (blockDim.x >> 6) + (threadIdx.x >> 6);
    int lane = threadIdx.x & 63;
    if (row >= M) return;
    const float4* p = (const float4*)(batch + (size_t)row * E);
    int n4 = E >> 2;
    for (int i = lane; i < n4; i += 64) {
        float4 v = p[i];
        f16x4 h;
        h.x = (f16)v.x; h.y = (f16)v.y; h.z = (f16)v.z; h.w = (f16)v.w;
        *(f16x4*)&ah[(size_t)row * E + i * 4] = h;
    }
}

// ---------------- init group-max array ----------------
__global__ void init_bmax_kernel(unsigned* __restrict__ bmax, int n) {
    int i = blockIdx.x * blockDim.x + threadIdx.x;
    for (; i < n; i += gridDim.x * blockDim.x) bmax[i] = 0u;  // ordered(-inf)
}

// ---------------- pass 1: hi*hi MFMA GEMM + per-(row,64col-group) max ----------------
// Round-11 geometry (BM=256xBN=128, 8 waves — tile-scan peak) restructured to the
// T3-minimum 2-phase recipe: BK 64->32 so double-buffer fits the same 48 KB;
// per K-step: issue stage(t+1) FIRST, then ds_read+MFMA on tile t, then ONE
// barrier (vmcnt(0) drain lands a full compute phase after issue).
// Involution swizzle re-derived for 64 B rows: key = (row>>1)&3.
#define BM 256
#define BN 128
#define BKH 32   // K halfs per step

__global__ __launch_bounds__(512, 4) void nn_hh_kernel(
    const f16* __restrict__ Ah, const f16* __restrict__ Bh,
    const float* __restrict__ rinvP, unsigned* __restrict__ bmax,
    int M, int V, int E, int NG)
{
    __shared__ f16 sA[2][BM * BKH];   // 2 x 16 KB
    __shared__ f16 sB[2][BN * BKH];   // 2 x  8 KB

    const int tid  = threadIdx.x;
    const int lane = tid & 63;
    const int w    = tid >> 6;      // wave 0..7
    const int wr   = w >> 1;        // wave row 0..3 (64 rows each)
    const int wc   = w & 1;         // wave col 0..1 (64 cols each)
    const int fr   = lane & 15;
    const int kg   = lane >> 4;     // 0..3

    const int row0 = blockIdx.x * BM;   // M block
    const int col0 = blockIdx.y * BN;   // N (V) block

    // staging: 64 lanes x 16B = 16 rows x 64B per issue; pre-swizzled source
    const int r4   = lane >> 2;             // row within 16-row issue group
    const int sl   = lane & 3;              // 16B slot within 64B row
    const int xsl  = sl ^ ((r4 >> 1) & 3);  // involution key (row>>1)&3
    int aoff[2], ldofA[2];
    #pragma unroll
    for (int it = 0; it < 2; ++it) {        // A: 2 issues/wave (8w x 2 x 16 = 256 rows)
        int rl = w * 32 + it * 16 + r4;
        aoff[it]  = (row0 + rl) * E + xsl * 8;
        ldofA[it] = (w * 32 + it * 16) * BKH;
    }
    int boff, ldofB;
    {                                        // B: 1 issue/wave (8w x 16 = 128 rows)
        int rl = w * 16 + r4;
        int bj = col0 + rl; if (bj > V - 1) bj = V - 1;
        boff  = bj * E + xsl * 8;
        ldofB = (w * 16) * BKH;
    }

    f32x4 acc[4][4];
    #pragma unroll
    for (int m = 0; m < 4; ++m)
        #pragma unroll
        for (int n = 0; n < 4; ++n) acc[m][n] = (f32x4){0.f, 0.f, 0.f, 0.f};

    const int steps = E / BKH;   // 16
    const int rslot = kg ^ ((fr >> 1) & 3);  // read-side involution (row ≡ fr mod 16)

    // prologue: stage tile 0 into buf 0, drain at barrier
    llds16(Ah + aoff[0], &sA[0][ldofA[0]]);
    llds16(Ah + aoff[1], &sA[0][ldofA[1]]);
    llds16(Bh + boff,    &sB[0][ldofB]);
    __syncthreads();

    int cur = 0;
    #pragma unroll 1
    for (int ks = 0; ks < steps; ++ks) {
        // (1) issue next tile's staging FIRST (drained at this iter's end barrier)
        if (ks + 1 < steps) {
            const int kadv = (ks + 1) * BKH;
            llds16(Ah + aoff[0] + kadv, &sA[cur ^ 1][ldofA[0]]);
            llds16(Ah + aoff[1] + kadv, &sA[cur ^ 1][ldofA[1]]);
            llds16(Bh + boff    + kadv, &sB[cur ^ 1][ldofB]);
        }

        // (2) ds_read fragments of current tile
        f16x8 ah[4], bh[4];
        #pragma unroll
        for (int m = 0; m < 4; ++m) {
            int row = wr * 64 + m * 16 + fr;
            ah[m] = *(const f16x8*)&sA[cur][row * BKH + rslot * 8];
        }
        #pragma unroll
        for (int n = 0; n < 4; ++n) {
            int col = wc * 64 + n * 16 + fr;
            bh[n] = *(const f16x8*)&sB[cur][col * BKH + rslot * 8];
        }

        // (3) 16 MFMA
        __builtin_amdgcn_s_setprio(1);
        #pragma unroll
        for (int m = 0; m < 4; ++m)
            #pragma unroll
            for (int n = 0; n < 4; ++n)
                acc[m][n] = __builtin_amdgcn_mfma_f32_16x16x32_f16(
                    ah[m], bh[n], acc[m][n], 0, 0, 0);
        __builtin_amdgcn_s_setprio(0);

        __syncthreads();   // drains staging issued at (1), one compute phase later
        cur ^= 1;
    }

    // epilogue: s = dot_hh * rinv[j]; per-(row, 64-col group) max, f32 only
    const int colb = col0 + wc * 64;
    const int g    = colb >> 6;
    float ri[4];
    #pragma unroll
    for (int n = 0; n < 4; ++n) {
        int j = colb + n * 16 + fr;
        ri[n] = (j < V) ? rinvP[j] : 0.f;
    }
    #pragma unroll
    for (int m = 0; m < 4; ++m) {
        #pragma unroll
        for (int r = 0; r < 4; ++r) {
            float best = -3.4e38f;
            #pragma unroll
            for (int n = 0; n < 4; ++n) {
                int j = colb + n * 16 + fr;
                float sc = (j < V) ? acc[m][n][r] * ri[n] : -3.4e38f;
                best = fmaxf(best, sc);
            }
            #pragma unroll
            for (int o = 8; o > 0; o >>= 1)
                best = fmaxf(best, __shfl_xor(best, o, 64));
            if (fr == 0) {
                int row = row0 + wr * 64 + m * 16 + kg * 4 + r;
                unsigned u = __float_as_uint(best);
                u = (u & 0x80000000u) ? ~u : (u | 0x80000000u);
                atomicMax(&bmax[(size_t)row * NG + g], u);
            }
        }
    }
}

// ---------------- pass 2: flag groups within TAU of row max; exact fp32 refine ----------------
#define TAU 0.008f
#define NGMAX 800

__global__ __launch_bounds__(256) void refine_kernel(
    const float* __restrict__ batch, const float* __restrict__ emb,
    const float* __restrict__ rinvP, const unsigned* __restrict__ bmax,
    int* __restrict__ out, int V, int E, int NG)
{
    const int r   = blockIdx.x;
    const int tid = threadIdx.x;
    __shared__ float arow[512];
    __shared__ float gv[NGMAX];
    __shared__ float part[4][64];
    __shared__ int   lst[NGMAX];
    __shared__ int   cnt;
    __shared__ float wmax[4];

    for (int i = tid; i < E; i += 256) arow[i] = batch[(size_t)r * E + i];
    if (tid == 0) cnt = 0;

    float lm = -3.4e38f;
    for (int g = tid; g < NG; g += 256) {
        unsigned u = bmax[(size_t)r * NG + g];
        unsigned v = (u & 0x80000000u) ? (u & 0x7FFFFFFFu) : ~u;  // un-order
        float f = __uint_as_float(v);
        gv[g] = f;
        lm = fmaxf(lm, f);
    }
    #pragma unroll
    for (int o = 32; o > 0; o >>= 1) lm = fmaxf(lm, __shfl_xor(lm, o, 64));
    if ((tid & 63) == 0) wmax[tid >> 6] = lm;
    __syncthreads();
    const float m1 = fmaxf(fmaxf(wmax[0], wmax[1]), fmaxf(wmax[2], wmax[3]));
    const float thresh = m1 - TAU;

    for (int g = tid; g < NG; g += 256)
        if (gv[g] >= thresh) { int i = atomicAdd(&cnt, 1); lst[i] = g; }
    __syncthreads();
    const int n = cnt;

    const int colL = tid & 63;
    const int kq   = tid >> 6;    // K quarter 0..3
    unsigned long long best = 0ULL;
    for (int li = 0; li < n; ++li) {
        const int j = lst[li] * 64 + colL;
        float p = 0.f;
        if (j < V) {
            const float4* bp = (const float4*)(emb + (size_t)j * E + kq * 128);
            const float4* ap = (const float4*)(&arow[kq * 128]);
            #pragma unroll 8
            for (int i = 0; i < 32; ++i) {
                float4 b = bp[i], a = ap[i];
                p = fmaf(a.x, b.x, p); p = fmaf(a.y, b.y, p);
                p = fmaf(a.z, b.z, p); p = fmaf(a.w, b.w, p);
            }
        }
        part[kq][colL] = p;
        __syncthreads();
        if (kq == 0 && j < V) {
            float dot = (part[0][colL] + part[1][colL]) +
                        (part[2][colL] + part[3][colL]);   // fixed order: deterministic
            unsigned long long key = pack_key(dot * rinvP[j], j);
            if (key > best) best = key;
        }
        __syncthreads();
    }

    if (tid < 64) {
        #pragma unroll
        for (int o = 32; o > 0; o >>= 1) {
            unsigned long long other = __shfl_xor(best, o, 64);
            if (other > best) best = other;
        }
        if (tid == 0) out[r] = (int)(~(unsigned)(best & 0xFFFFFFFFULL));
    }
}

// ================= fallback fp32 path (round-0, validated) =================
__global__ void init_keys_kernel(unsigned long long* __restrict__ keys, int M) {
    int i = blockIdx.x * blockDim.x + threadIdx.x;
    if (i < M) keys[i] = 0ULL;
}

__global__ void extract_kernel(const unsigned long long* __restrict__ keys,
                               int* __restrict__ out, int M) {
    int i = blockIdx.x * blockDim.x + threadIdx.x;
    if (i < M) out[i] = (int)(~(unsigned)(keys[i] & 0xFFFFFFFFULL));
}

__global__ void inv_norms_kernel(const float* __restrict__ emb,
                                 float* __restrict__ r, int V, int E) {
    int row  = blockIdx.x * (blockDim.x >> 6) + (threadIdx.x >> 6);
    int lane = threadIdx.x & 63;
    if (row >= V) return;
    const float4* p = reinterpret_cast<const float4*>(emb + (size_t)row * E);
    float ss = 0.f;
    int n4 = E >> 2;
    for (int i = lane; i < n4; i += 64) {
        float4 v = p[i];
        ss = fmaf(v.x, v.x, ss); ss = fmaf(v.y, v.y, ss);
        ss = fmaf(v.z, v.z, ss); ss = fmaf(v.w, v.w, ss);
    }
    #pragma unroll
    for (int o = 32; o > 0; o >>= 1) ss += __shfl_down(ss, o, 64);
    if (lane == 0) r[row] = 1.0f / sqrtf(ss);
}

#define FBM 128
#define FBN 128
#define FBK 32
#define LDSPAD 4

__global__ __launch_bounds__(256) void nn_gemm_argmax(
    const float* __restrict__ batch, const float* __restrict__ emb,
    const float* __restrict__ rinv, unsigned long long* __restrict__ keys,
    int M, int V, int E)
{
    __shared__ float As[FBK][FBM + LDSPAD];
    __shared__ float Bs[FBK][FBN + LDSPAD];
    const int tid = threadIdx.x;
    const int tx  = tid & 15;
    const int ty  = tid >> 4;
    const int row0 = blockIdx.y * FBM;
    const int col0 = blockIdx.x * FBN;
    float acc[8][8];
    #pragma unroll
    for (int i = 0; i < 8; ++i)
        #pragma unroll
        for (int j = 0; j < 8; ++j) acc[i][j] = 0.f;
    const int steps = E / FBK;
    for (int ks = 0; ks < steps; ++ks) {
        const int k0 = ks * FBK;
        #pragma unroll
        for (int it = 0; it < 4; ++it) {
            int idx = it * 256 + tid;
            int rr = idx >> 3, cc = idx & 7;
            float4 v = *reinterpret_cast<const float4*>(
                &batch[(size_t)(row0 + rr) * E + k0 + cc * 4]);
            As[cc*4+0][rr] = v.x; As[cc*4+1][rr] = v.y;
            As[cc*4+2][rr] = v.z; As[cc*4+3][rr] = v.w;
        }
        #pragma unroll
        for (int it = 0; it < 4; ++it) {
            int idx = it * 256 + tid;
            int rr = idx >> 3, cc = idx & 7;
            int j = col0 + rr;
            float4 v = make_float4(0.f,0.f,0.f,0.f);
            if (j < V)
                v = *reinterpret_cast<const float4*>(&emb[(size_t)j * E + k0 + cc * 4]);
            Bs[cc*4+0][rr] = v.x; Bs[cc*4+1][rr] = v.y;
            Bs[cc*4+2][rr] = v.z; Bs[cc*4+3][rr] = v.w;
        }
        __syncthreads();
        #pragma unroll
        for (int k = 0; k < FBK; ++k) {
            float4 a0 = *reinterpret_cast<const float4*>(&As[k][ty*8]);
            float4 a1 = *reinterpret_cast<const float4*>(&As[k][ty*8+4]);
            float4 b0 = *reinterpret_cast<const float4*>(&Bs[k][tx*8]);
            float4 b1 = *reinterpret_cast<const float4*>(&Bs[k][tx*8+4]);
            float a[8] = {a0.x,a0.y,a0.z,a0.w,a1.x,a1.y,a1.z,a1.w};
            float b[8] = {b0.x,b0.y,b0.z,b0.w,b1.x,b1.y,b1.z,b1.w};
            #pragma unroll
            for (int i = 0; i < 8; ++i)
                #pragma unroll
                for (int jj = 0; jj < 8; ++jj)
                    acc[i][jj] = fmaf(a[i], b[jj], acc[i][jj]);
        }
        __syncthreads();
    }
    #pragma unroll
    for (int i = 0; i < 8; ++i) {
        const int q = row0 + ty * 8 + i;
        unsigned long long best = 0ULL;
        #pragma unroll
        for (int jj = 0; jj < 8; ++jj) {
            int j = col0 + tx * 8 + jj;
            if (j < V) {
                unsigned long long key = pack_key(acc[i][jj] * rinv[j], j);
                if (key > best) best = key;
            }
        }
        #pragma unroll
        for (int o = 8; o > 0; o >>= 1) {
            unsigned long long other = __shfl_xor(best, o, 64);
            if (other > best) best = other;
        }
        if (tx == 0 && best != 0ULL) atomicMax(&keys[q], best);
    }
}

// ================= launch =================
extern "C" void kernel_launch(void* const* d_in, const int* in_sizes, int n_in,
                              void* d_out, int out_size, void* d_ws, size_t ws_size,
                              hipStream_t stream) {
    const float* batch = (const float*)d_in[0];  // [B,S,E] f32
    const float* emb   = (const float*)d_in[1];  // [V,E]   f32
    int* out = (int*)d_out;

    const int M = out_size;                 // 4096
    const int E = in_sizes[0] / M;          // 512
    const int V = in_sizes[1] / E;          // 50000
    const int NG = (V + 63) / 64;           // 782 groups of 64 cols

    auto al256 = [](size_t x) { return (x + 255) & ~(size_t)255; };
    size_t o_rinv = 0;
    size_t o_keys = al256(o_rinv + (size_t)V * 4);
    size_t o_bmax = al256(o_keys + (size_t)M * 8);
    size_t o_Ah   = al256(o_bmax + (size_t)M * NG * 4);
    size_t o_Bh   = al256(o_Ah  + (size_t)M * E * 2);
    size_t need   = al256(o_Bh  + (size_t)V * E * 2);

    float* rinv = (float*)((char*)d_ws + o_rinv);
    unsigned long long* keys = (unsigned long long*)((char*)d_ws + o_keys);
    unsigned* bmax = (unsigned*)((char*)d_ws + o_bmax);

    if (ws_size >= need && E == 512 && (M % BM) == 0 && NG <= NGMAX) {
        f16* Ah = (f16*)((char*)d_ws + o_Ah);
        f16* Bh = (f16*)((char*)d_ws + o_Bh);

        convert_emb_kernel<<<(V + 3) / 4, 256, 0, stream>>>(emb, Bh, rinv, V, E);
        convert_batch_kernel<<<(M + 3) / 4, 256, 0, stream>>>(batch, Ah, M, E);
        init_bmax_kernel<<<2048, 256, 0, stream>>>(bmax, M * NG);

        dim3 grid(M / BM, (V + BN - 1) / BN);   // 16 x 391
        nn_hh_kernel<<<grid, 512, 0, stream>>>(Ah, Bh, rinv, bmax, M, V, E, NG);

        refine_kernel<<<M, 256, 0, stream>>>(batch, emb, rinv, bmax, out, V, E, NG);
    } else {
        inv_norms_kernel<<<(V + 3) / 4, 256, 0, stream>>>(emb, rinv, V, E);
        init_keys_kernel<<<(M + 255) / 256, 256, 0, stream>>>(keys, M);
        dim3 grid((V + FBN - 1) / FBN, M / FBM);
        nn_gemm_argmax<<<grid, 256, 0, stream>>>(batch, emb, rinv, keys, M, V, E);
        extract_kernel<<<(M + 255) / 256, 256, 0, stream>>>(keys, out, M);
    }
}

// Round 15
// 387.707 us; speedup vs baseline: 1.0739x; 1.0739x over previous
//
#include <hip/hip_runtime.h>
#include <stdint.h>

typedef _Float16 f16;
typedef _Float16 f16x4 __attribute__((ext_vector_type(4)));
typedef _Float16 f16x8 __attribute__((ext_vector_type(8)));
typedef float    f32x4 __attribute__((ext_vector_type(4)));

__device__ __forceinline__ void llds16(const void* g, void* l) {
    __builtin_amdgcn_global_load_lds(
        (const __attribute__((address_space(1))) void*)g,
        (__attribute__((address_space(3))) void*)l, 16, 0, 0);
}

__device__ __forceinline__ unsigned long long pack_key(float s, int j) {
    unsigned u = __float_as_uint(s);
    u = (u & 0x80000000u) ? ~u : (u | 0x80000000u);
    return ((unsigned long long)u << 32) | (unsigned)(~(unsigned)j);
}

// ---------------- convert emb -> Bh fp16 + plain rinv ----------------
__global__ void convert_emb_kernel(const float* __restrict__ emb,
                                   f16* __restrict__ bh,
                                   float* __restrict__ rinv, int V, int E) {
    int row  = blockIdx.x * (blockDim.x >> 6) + (threadIdx.x >> 6);
    int lane = threadIdx.x & 63;
    if (row >= V) return;
    const float4* p = (const float4*)(emb + (size_t)row * E);
    int n4 = E >> 2;
    float ss = 0.f;
    for (int i = lane; i < n4; i += 64) {
        float4 v = p[i];
        ss = fmaf(v.x, v.x, ss); ss = fmaf(v.y, v.y, ss);
        ss = fmaf(v.z, v.z, ss); ss = fmaf(v.w, v.w, ss);
    }
    #pragma unroll
    for (int o = 32; o > 0; o >>= 1) ss += __shfl_down(ss, o, 64);
    if (lane == 0) rinv[row] = 1.0f / sqrtf(ss);

    for (int i = lane; i < n4; i += 64) {
        float4 v = p[i];
        f16x4 h;
        h.x = (f16)v.x; h.y = (f16)v.y; h.z = (f16)v.z; h.w = (f16)v.w;
        *(f16x4*)&bh[(size_t)row * E + i * 4] = h;
    }
}

// ---------------- convert batch -> Ah fp16 ----------------
__global__ void convert_batch_kernel(const float* __restrict__ batch,
                                     f16* __restrict__ ah, int M, int E) {
    int row  = blockIdx.x * (blockDim.x >> 6) + (threadIdx.x >> 6);
    int lane = threadIdx.x & 63;
    if (row >= M) return;
    const float4* p = (const float4*)(batch + (size_t)row * E);
    int n4 = E >> 2;
    for (int i = lane; i < n4; i += 64) {
        float4 v = p[i];
        f16x4 h;
        h.x = (f16)v.x; h.y = (f16)v.y; h.z = (f16)v.z; h.w = (f16)v.w;
        *(f16x4*)&ah[(size_t)row * E + i * 4] = h;
    }
}

// ---------------- init group-max array ----------------
__global__ void init_bmax_kernel(unsigned* __restrict__ bmax, int n) {
    int i = blockIdx.x * blockDim.x + threadIdx.x;
    for (; i < n; i += gridDim.x * blockDim.x) bmax[i] = 0u;  // ordered(-inf)
}

// ---------------- pass 1: hi*hi MFMA GEMM + per-(row,64col-group) max ----------------
// Final configuration (validated rounds 11/13): BM=256 x BN=128, 8 waves,
// 2-barrier schedule, involution swizzle (pre-swizzled gload source + XOR'd
// ds_read -> 0 bank conflicts), f32-only group-max epilogue.
// Falsified alternatives: BM 128 (27%) / 512 (25.6%) vs 256 (35.5% MfmaUtil);
// B-direct-global (19%); 2-phase BK=32 (31%); 8-phase ports x3 (~31%); i8 (wrong).
#define BM 256
#define BN 128
#define BKH 64   // K halfs per step

__global__ __launch_bounds__(512, 4) void nn_hh_kernel(
    const f16* __restrict__ Ah, const f16* __restrict__ Bh,
    const float* __restrict__ rinvP, unsigned* __restrict__ bmax,
    int M, int V, int E, int NG)
{
    __shared__ f16 sA[BM * BKH];   // 32 KB
    __shared__ f16 sB[BN * BKH];   // 16 KB

    const int tid  = threadIdx.x;
    const int lane = tid & 63;
    const int w    = tid >> 6;      // wave 0..7
    const int wr   = w >> 1;        // wave row 0..3 (64 rows each)
    const int wc   = w & 1;         // wave col 0..1 (64 cols each)
    const int fr   = lane & 15;
    const int kg   = lane >> 4;     // 0..3

    const int row0 = blockIdx.x * BM;   // M block
    const int col0 = blockIdx.y * BN;   // N (V) block

    // staging: lane -> (row within 8-row group, 16B slot); pre-swizzled source
    const int srow  = lane >> 3;
    const int sslot = lane & 7;
    const int xslot = sslot ^ srow;
    int aoff[4], ldofA[4];
    #pragma unroll
    for (int it = 0; it < 4; ++it) {            // A: 4 issues/wave, 32 rows
        int rl = w * 32 + it * 8 + srow;
        aoff[it]  = (row0 + rl) * E + xslot * 8;
        ldofA[it] = (w * 32 + it * 8) * BKH;
    }
    int boff[2], ldofB[2];
    #pragma unroll
    for (int it = 0; it < 2; ++it) {            // B: 2 issues/wave, 16 rows
        int rl = w * 16 + it * 8 + srow;
        int bj = col0 + rl; if (bj > V - 1) bj = V - 1;
        boff[it]  = bj * E + xslot * 8;
        ldofB[it] = (w * 16 + it * 8) * BKH;
    }

    f32x4 acc[4][4];
    #pragma unroll
    for (int m = 0; m < 4; ++m)
        #pragma unroll
        for (int n = 0; n < 4; ++n) acc[m][n] = (f32x4){0.f, 0.f, 0.f, 0.f};

    const int steps = E / BKH;   // 8
    for (int ks = 0; ks < steps; ++ks) {
        const int kadv = ks * BKH;
        #pragma unroll
        for (int it = 0; it < 4; ++it)
            llds16(Ah + aoff[it] + kadv, sA + ldofA[it]);
        #pragma unroll
        for (int it = 0; it < 2; ++it)
            llds16(Bh + boff[it] + kadv, sB + ldofB[it]);
        __syncthreads();

        #pragma unroll
        for (int ksub = 0; ksub < 2; ++ksub) {
            f16x8 ah[4], bh[4];
            #pragma unroll
            for (int m = 0; m < 4; ++m) {
                int row = wr * 64 + m * 16 + fr;
                int off = row * BKH + (((ksub * 4 + kg) ^ (fr & 7)) << 3);
                ah[m] = *(const f16x8*)&sA[off];
            }
            #pragma unroll
            for (int n = 0; n < 4; ++n) {
                int col = wc * 64 + n * 16 + fr;
                int off = col * BKH + (((ksub * 4 + kg) ^ (fr & 7)) << 3);
                bh[n] = *(const f16x8*)&sB[off];
            }
            #pragma unroll
            for (int m = 0; m < 4; ++m)
                #pragma unroll
                for (int n = 0; n < 4; ++n)
                    acc[m][n] = __builtin_amdgcn_mfma_f32_16x16x32_f16(
                        ah[m], bh[n], acc[m][n], 0, 0, 0);
        }
        __syncthreads();
    }

    // epilogue: s = dot_hh * rinv[j]; per-(row, 64-col group) max, f32 only
    const int colb = col0 + wc * 64;
    const int g    = colb >> 6;
    float ri[4];
    #pragma unroll
    for (int n = 0; n < 4; ++n) {
        int j = colb + n * 16 + fr;
        ri[n] = (j < V) ? rinvP[j] : 0.f;
    }
    #pragma unroll
    for (int m = 0; m < 4; ++m) {
        #pragma unroll
        for (int r = 0; r < 4; ++r) {
            float best = -3.4e38f;
            #pragma unroll
            for (int n = 0; n < 4; ++n) {
                int j = colb + n * 16 + fr;
                float sc = (j < V) ? acc[m][n][r] * ri[n] : -3.4e38f;
                best = fmaxf(best, sc);
            }
            #pragma unroll
            for (int o = 8; o > 0; o >>= 1)
                best = fmaxf(best, __shfl_xor(best, o, 64));
            if (fr == 0) {
                int row = row0 + wr * 64 + m * 16 + kg * 4 + r;
                unsigned u = __float_as_uint(best);
                u = (u & 0x80000000u) ? ~u : (u | 0x80000000u);
                atomicMax(&bmax[(size_t)row * NG + g], u);
            }
        }
    }
}

// ---------------- pass 2: flag groups within TAU of row max; exact fp32 refine ----------------
#define TAU 0.008f
#define NGMAX 800

__global__ __launch_bounds__(256) void refine_kernel(
    const float* __restrict__ batch, const float* __restrict__ emb,
    const float* __restrict__ rinvP, const unsigned* __restrict__ bmax,
    int* __restrict__ out, int V, int E, int NG)
{
    const int r   = blockIdx.x;
    const int tid = threadIdx.x;
    __shared__ float arow[512];
    __shared__ float gv[NGMAX];
    __shared__ float part[4][64];
    __shared__ int   lst[NGMAX];
    __shared__ int   cnt;
    __shared__ float wmax[4];

    for (int i = tid; i < E; i += 256) arow[i] = batch[(size_t)r * E + i];
    if (tid == 0) cnt = 0;

    float lm = -3.4e38f;
    for (int g = tid; g < NG; g += 256) {
        unsigned u = bmax[(size_t)r * NG + g];
        unsigned v = (u & 0x80000000u) ? (u & 0x7FFFFFFFu) : ~u;  // un-order
        float f = __uint_as_float(v);
        gv[g] = f;
        lm = fmaxf(lm, f);
    }
    #pragma unroll
    for (int o = 32; o > 0; o >>= 1) lm = fmaxf(lm, __shfl_xor(lm, o, 64));
    if ((tid & 63) == 0) wmax[tid >> 6] = lm;
    __syncthreads();
    const float m1 = fmaxf(fmaxf(wmax[0], wmax[1]), fmaxf(wmax[2], wmax[3]));
    const float thresh = m1 - TAU;

    for (int g = tid; g < NG; g += 256)
        if (gv[g] >= thresh) { int i = atomicAdd(&cnt, 1); lst[i] = g; }
    __syncthreads();
    const int n = cnt;

    const int colL = tid & 63;
    const int kq   = tid >> 6;    // K quarter 0..3
    unsigned long long best = 0ULL;
    for (int li = 0; li < n; ++li) {
        const int j = lst[li] * 64 + colL;
        float p = 0.f;
        if (j < V) {
            const float4* bp = (const float4*)(emb + (size_t)j * E + kq * 128);
            const float4* ap = (const float4*)(&arow[kq * 128]);
            #pragma unroll 8
            for (int i = 0; i < 32; ++i) {
                float4 b = bp[i], a = ap[i];
                p = fmaf(a.x, b.x, p); p = fmaf(a.y, b.y, p);
                p = fmaf(a.z, b.z, p); p = fmaf(a.w, b.w, p);
            }
        }
        part[kq][colL] = p;
        __syncthreads();
        if (kq == 0 && j < V) {
            float dot = (part[0][colL] + part[1][colL]) +
                        (part[2][colL] + part[3][colL]);   // fixed order: deterministic
            unsigned long long key = pack_key(dot * rinvP[j], j);
            if (key > best) best = key;
        }
        __syncthreads();
    }

    if (tid < 64) {
        #pragma unroll
        for (int o = 32; o > 0; o >>= 1) {
            unsigned long long other = __shfl_xor(best, o, 64);
            if (other > best) best = other;
        }
        if (tid == 0) out[r] = (int)(~(unsigned)(best & 0xFFFFFFFFULL));
    }
}

// ================= fallback fp32 path (round-0, validated) =================
__global__ void init_keys_kernel(unsigned long long* __restrict__ keys, int M) {
    int i = blockIdx.x * blockDim.x + threadIdx.x;
    if (i < M) keys[i] = 0ULL;
}

__global__ void extract_kernel(const unsigned long long* __restrict__ keys,
                               int* __restrict__ out, int M) {
    int i = blockIdx.x * blockDim.x + threadIdx.x;
    if (i < M) out[i] = (int)(~(unsigned)(keys[i] & 0xFFFFFFFFULL));
}

__global__ void inv_norms_kernel(const float* __restrict__ emb,
                                 float* __restrict__ r, int V, int E) {
    int row  = blockIdx.x * (blockDim.x >> 6) + (threadIdx.x >> 6);
    int lane = threadIdx.x & 63;
    if (row >= V) return;
    const float4* p = reinterpret_cast<const float4*>(emb + (size_t)row * E);
    float ss = 0.f;
    int n4 = E >> 2;
    for (int i = lane; i < n4; i += 64) {
        float4 v = p[i];
        ss = fmaf(v.x, v.x, ss); ss = fmaf(v.y, v.y, ss);
        ss = fmaf(v.z, v.z, ss); ss = fmaf(v.w, v.w, ss);
    }
    #pragma unroll
    for (int o = 32; o > 0; o >>= 1) ss += __shfl_down(ss, o, 64);
    if (lane == 0) r[row] = 1.0f / sqrtf(ss);
}

#define FBM 128
#define FBN 128
#define FBK 32
#define LDSPAD 4

__global__ __launch_bounds__(256) void nn_gemm_argmax(
    const float* __restrict__ batch, const float* __restrict__ emb,
    const float* __restrict__ rinv, unsigned long long* __restrict__ keys,
    int M, int V, int E)
{
    __shared__ float As[FBK][FBM + LDSPAD];
    __shared__ float Bs[FBK][FBN + LDSPAD];
    const int tid = threadIdx.x;
    const int tx  = tid & 15;
    const int ty  = tid >> 4;
    const int row0 = blockIdx.y * FBM;
    const int col0 = blockIdx.x * FBN;
    float acc[8][8];
    #pragma unroll
    for (int i = 0; i < 8; ++i)
        #pragma unroll
        for (int j = 0; j < 8; ++j) acc[i][j] = 0.f;
    const int steps = E / FBK;
    for (int ks = 0; ks < steps; ++ks) {
        const int k0 = ks * FBK;
        #pragma unroll
        for (int it = 0; it < 4; ++it) {
            int idx = it * 256 + tid;
            int rr = idx >> 3, cc = idx & 7;
            float4 v = *reinterpret_cast<const float4*>(
                &batch[(size_t)(row0 + rr) * E + k0 + cc * 4]);
            As[cc*4+0][rr] = v.x; As[cc*4+1][rr] = v.y;
            As[cc*4+2][rr] = v.z; As[cc*4+3][rr] = v.w;
        }
        #pragma unroll
        for (int it = 0; it < 4; ++it) {
            int idx = it * 256 + tid;
            int rr = idx >> 3, cc = idx & 7;
            int j = col0 + rr;
            float4 v = make_float4(0.f,0.f,0.f,0.f);
            if (j < V)
                v = *reinterpret_cast<const float4*>(&emb[(size_t)j * E + k0 + cc * 4]);
            Bs[cc*4+0][rr] = v.x; Bs[cc*4+1][rr] = v.y;
            Bs[cc*4+2][rr] = v.z; Bs[cc*4+3][rr] = v.w;
        }
        __syncthreads();
        #pragma unroll
        for (int k = 0; k < FBK; ++k) {
            float4 a0 = *reinterpret_cast<const float4*>(&As[k][ty*8]);
            float4 a1 = *reinterpret_cast<const float4*>(&As[k][ty*8+4]);
            float4 b0 = *reinterpret_cast<const float4*>(&Bs[k][tx*8]);
            float4 b1 = *reinterpret_cast<const float4*>(&Bs[k][tx*8+4]);
            float a[8] = {a0.x,a0.y,a0.z,a0.w,a1.x,a1.y,a1.z,a1.w};
            float b[8] = {b0.x,b0.y,b0.z,b0.w,b1.x,b1.y,b1.z,b1.w};
            #pragma unroll
            for (int i = 0; i < 8; ++i)
                #pragma unroll
                for (int jj = 0; jj < 8; ++jj)
                    acc[i][jj] = fmaf(a[i], b[jj], acc[i][jj]);
        }
        __syncthreads();
    }
    #pragma unroll
    for (int i = 0; i < 8; ++i) {
        const int q = row0 + ty * 8 + i;
        unsigned long long best = 0ULL;
        #pragma unroll
        for (int jj = 0; jj < 8; ++jj) {
            int j = col0 + tx * 8 + jj;
            if (j < V) {
                unsigned long long key = pack_key(acc[i][jj] * rinv[j], j);
                if (key > best) best = key;
            }
        }
        #pragma unroll
        for (int o = 8; o > 0; o >>= 1) {
            unsigned long long other = __shfl_xor(best, o, 64);
            if (other > best) best = other;
        }
        if (tx == 0 && best != 0ULL) atomicMax(&keys[q], best);
    }
}

// ================= launch =================
extern "C" void kernel_launch(void* const* d_in, const int* in_sizes, int n_in,
                              void* d_out, int out_size, void* d_ws, size_t ws_size,
                              hipStream_t stream) {
    const float* batch = (const float*)d_in[0];  // [B,S,E] f32
    const float* emb   = (const float*)d_in[1];  // [V,E]   f32
    int* out = (int*)d_out;

    const int M = out_size;                 // 4096
    const int E = in_sizes[0] / M;          // 512
    const int V = in_sizes[1] / E;          // 50000
    const int NG = (V + 63) / 64;           // 782 groups of 64 cols

    auto al256 = [](size_t x) { return (x + 255) & ~(size_t)255; };
    size_t o_rinv = 0;
    size_t o_keys = al256(o_rinv + (size_t)V * 4);
    size_t o_bmax = al256(o_keys + (size_t)M * 8);
    size_t o_Ah   = al256(o_bmax + (size_t)M * NG * 4);
    size_t o_Bh   = al256(o_Ah  + (size_t)M * E * 2);
    size_t need   = al256(o_Bh  + (size_t)V * E * 2);

    float* rinv = (float*)((char*)d_ws + o_rinv);
    unsigned long long* keys = (unsigned long long*)((char*)d_ws + o_keys);
    unsigned* bmax = (unsigned*)((char*)d_ws + o_bmax);

    if (ws_size >= need && E == 512 && (M % BM) == 0 && NG <= NGMAX) {
        f16* Ah = (f16*)((char*)d_ws + o_Ah);
        f16* Bh = (f16*)((char*)d_ws + o_Bh);

        convert_emb_kernel<<<(V + 3) / 4, 256, 0, stream>>>(emb, Bh, rinv, V, E);
        convert_batch_kernel<<<(M + 3) / 4, 256, 0, stream>>>(batch, Ah, M, E);
        init_bmax_kernel<<<2048, 256, 0, stream>>>(bmax, M * NG);

        dim3 grid(M / BM, (V + BN - 1) / BN);   // 16 x 391
        nn_hh_kernel<<<grid, 512, 0, stream>>>(Ah, Bh, rinv, bmax, M, V, E, NG);

        refine_kernel<<<M, 256, 0, stream>>>(batch, emb, rinv, bmax, out, V, E, NG);
    } else {
        inv_norms_kernel<<<(V + 3) / 4, 256, 0, stream>>>(emb, rinv, V, E);
        init_keys_kernel<<<(M + 255) / 256, 256, 0, stream>>>(keys, M);
        dim3 grid((V + FBN - 1) / FBN, M / FBM);
        nn_gemm_argmax<<<grid, 256, 0, stream>>>(batch, emb, rinv, keys, M, V, E);
        extract_kernel<<<(M + 255) / 256, 256, 0, stream>>>(keys, out, M);
    }
}